// Round 1
// baseline (74.323 us; speedup 1.0000x reference)
//
#include <hip/hip_runtime.h>
#include <math.h>

// LDAWordGenerator: z[b,v] = logsumexp_t(log_theta[b,t] + log_phi[t,v])
// Factored: z = mu_v + log( sum_t Ea[b,t] * Ew[t,v] )  (see analysis)
// B=128, T=128, V=32000.

constexpr int B = 128;
constexpr int T = 128;
constexpr int V = 32000;
constexpr int VC = 64;            // V-columns per block in main kernel
constexpr int KPARTS = 4;         // partial splits per w-row for lse_w
constexpr int PART = V / KPARTS;  // 8000

// ws layout (floats): Ea[T*B] | pm[T*KPARTS] | ps[T*KPARTS] | c[T]
constexpr int WS_EA = 0;
constexpr int WS_PM = T * B;               // 16384
constexpr int WS_PS = WS_PM + T * KPARTS;  // +512
constexpr int WS_C  = WS_PS + T * KPARTS;  // +512

// ---------------- K1: partial online logsumexp over each w row ----------------
__global__ __launch_bounds__(256) void k_lsew_partial(const float* __restrict__ w,
                                                      float* __restrict__ pm,
                                                      float* __restrict__ ps) {
    const int t = blockIdx.x >> 2;
    const int part = blockIdx.x & 3;
    const float* row = w + (size_t)t * V + (size_t)part * PART;

    float m = -INFINITY, s = 0.f;
    for (int v = threadIdx.x; v < PART; v += 256) {
        float x = row[v];
        if (x > m) { s = s * __expf(m - x) + 1.f; m = x; }
        else       { s += __expf(x - m); }
    }
    __shared__ float sm[256], ss[256];
    sm[threadIdx.x] = m; ss[threadIdx.x] = s;
    __syncthreads();
    for (int off = 128; off > 0; off >>= 1) {
        if (threadIdx.x < off) {
            float m1 = sm[threadIdx.x],       s1 = ss[threadIdx.x];
            float m2 = sm[threadIdx.x + off], s2 = ss[threadIdx.x + off];
            float M = fmaxf(m1, m2);
            sm[threadIdx.x] = M;
            ss[threadIdx.x] = s1 * __expf(m1 - M) + s2 * __expf(m2 - M);
        }
        __syncthreads();
    }
    if (threadIdx.x == 0) {
        pm[blockIdx.x] = sm[0];
        ps[blockIdx.x] = ss[0];
    }
}

// ---------------- K2: lse_in, g_t, c_t, Ea ----------------
__global__ __launch_bounds__(128) void k_prep(const float* __restrict__ inp,
                                              const float* __restrict__ pm,
                                              const float* __restrict__ ps,
                                              float* __restrict__ c_out,
                                              float* __restrict__ Ea) {
    __shared__ float lse_in[B];
    __shared__ float gt[T];
    const int tid = threadIdx.x;

    // lse_in[b] (thread = b, serial over T=128)
    {
        const float* row = inp + (size_t)tid * T;
        float m = -INFINITY;
        for (int t = 0; t < T; ++t) m = fmaxf(m, row[t]);
        float s = 0.f;
        for (int t = 0; t < T; ++t) s += __expf(row[t] - m);
        lse_in[tid] = m + logf(s);
    }
    __syncthreads();

    // lse_w[t] combine, g_t = max_b(log_theta[b,t]), c_t = g_t - lse_w[t]
    {
        const int t = tid;
        float M = pm[t * KPARTS];
        for (int p = 1; p < KPARTS; ++p) M = fmaxf(M, pm[t * KPARTS + p]);
        float S = 0.f;
        for (int p = 0; p < KPARTS; ++p) S += ps[t * KPARTS + p] * __expf(pm[t * KPARTS + p] - M);
        float lw = M + logf(S);
        float g = -INFINITY;
        for (int b = 0; b < B; ++b) g = fmaxf(g, inp[b * T + t] - lse_in[b]);
        gt[t] = g;
        c_out[t] = g - lw;
    }
    __syncthreads();

    // Ea[t][b] = exp(inp[b][t] - lse_in[b] - g_t)  (exponent in [-~10, 0])
    {
        const int b = tid;
        const float li = lse_in[b];
        for (int t = 0; t < T; ++t)
            Ea[t * B + b] = __expf(inp[b * T + t] - li - gt[t]);
    }
}

// ---------------- K3: main — mu_v, Ew, fp32 matmul, epilogue ----------------
__global__ __launch_bounds__(256) void k_main(const float* __restrict__ w,
                                              const float* __restrict__ c_in,
                                              const float* __restrict__ Ea_g,
                                              float* __restrict__ out) {
    __shared__ float Ea[T][B];    // 64 KiB
    __shared__ float Ew[T][VC];   // 32 KiB  (staged raw w, transformed in place)
    __shared__ float cs[T];
    __shared__ float mu[VC];
    __shared__ float pmax[4][VC];

    const int tid = threadIdx.x;
    const int vbase = blockIdx.x * VC;

    if (tid < T) cs[tid] = c_in[tid];

    // load Ea: 16384 floats = 4096 float4, 16 per thread
    {
        const float4* src = (const float4*)Ea_g;
        float4* dst = (float4*)&Ea[0][0];
        #pragma unroll
        for (int k = 0; k < 16; ++k) dst[tid + k * 256] = src[tid + k * 256];
    }
    // load w slab [T][VC] raw into Ew: 8192 floats = 2048 float4, 8 per thread
    {
        #pragma unroll
        for (int k = 0; k < 8; ++k) {
            int idx = tid + k * 256;    // over [T][VC/4] float4 grid
            int t = idx >> 4;           // 16 float4 per row
            int c4 = idx & 15;
            float4 val = *(const float4*)(w + (size_t)t * V + vbase + c4 * 4);
            *(float4*)&Ew[t][c4 * 4] = val;
        }
    }
    __syncthreads();

    // mu_v = max_t (w[t][v] + c_t): thread (v = tid&63, q = tid>>6) over t-quarter
    {
        const int v = tid & 63, q = tid >> 6;
        float m = -INFINITY;
        for (int t = q * 32; t < q * 32 + 32; ++t) m = fmaxf(m, Ew[t][v] + cs[t]);
        pmax[q][v] = m;
    }
    __syncthreads();
    if (tid < VC)
        mu[tid] = fmaxf(fmaxf(pmax[0][tid], pmax[1][tid]), fmaxf(pmax[2][tid], pmax[3][tid]));
    __syncthreads();

    // Ew in-place: exp(w + c_t - mu_v); 8192 elems, 32 per thread
    {
        #pragma unroll
        for (int k = 0; k < 32; ++k) {
            int idx = tid + k * 256;
            int t = idx >> 6, v = idx & 63;
            Ew[t][v] = __expf(Ew[t][v] + cs[t] - mu[v]);
        }
    }
    __syncthreads();

    // matmul: thread tile 8b x 4v. tv = tid&15 -> v0 = tv*4; tb = tid>>4 -> b0 = tb*8
    const int tv = tid & 15, tb = tid >> 4;
    const int v0 = tv * 4, b0 = tb * 8;

    float acc[8][4];
    #pragma unroll
    for (int i = 0; i < 8; ++i)
        #pragma unroll
        for (int j = 0; j < 4; ++j) acc[i][j] = 0.f;

    #pragma unroll 4
    for (int t = 0; t < T; ++t) {
        float4 ew = *(float4*)&Ew[t][v0];
        float4 ea0 = *(float4*)&Ea[t][b0];
        float4 ea1 = *(float4*)&Ea[t][b0 + 4];
        float ea[8] = {ea0.x, ea0.y, ea0.z, ea0.w, ea1.x, ea1.y, ea1.z, ea1.w};
        #pragma unroll
        for (int i = 0; i < 8; ++i) {
            acc[i][0] = fmaf(ea[i], ew.x, acc[i][0]);
            acc[i][1] = fmaf(ea[i], ew.y, acc[i][1]);
            acc[i][2] = fmaf(ea[i], ew.z, acc[i][2]);
            acc[i][3] = fmaf(ea[i], ew.w, acc[i][3]);
        }
    }

    // epilogue: z = mu_v + log(P)
    #pragma unroll
    for (int i = 0; i < 8; ++i) {
        const int b = b0 + i;
        float4 zz;
        zz.x = mu[v0 + 0] + __logf(acc[i][0]);
        zz.y = mu[v0 + 1] + __logf(acc[i][1]);
        zz.z = mu[v0 + 2] + __logf(acc[i][2]);
        zz.w = mu[v0 + 3] + __logf(acc[i][3]);
        *(float4*)(out + (size_t)b * V + vbase + v0) = zz;
    }
}

extern "C" void kernel_launch(void* const* d_in, const int* in_sizes, int n_in,
                              void* d_out, int out_size, void* d_ws, size_t ws_size,
                              hipStream_t stream) {
    const float* inp = (const float*)d_in[0];  // (B, T) f32
    const float* w   = (const float*)d_in[1];  // (T, V) f32
    float* out = (float*)d_out;                // (B, V) f32
    float* ws  = (float*)d_ws;

    float* Ea = ws + WS_EA;
    float* pm = ws + WS_PM;
    float* ps = ws + WS_PS;
    float* c  = ws + WS_C;

    k_lsew_partial<<<dim3(T * KPARTS), dim3(256), 0, stream>>>(w, pm, ps);
    k_prep<<<dim3(1), dim3(128), 0, stream>>>(inp, pm, ps, c, Ea);
    k_main<<<dim3(V / VC), dim3(256), 0, stream>>>(w, c, Ea, out);
}

// Round 2
// 62.296 us; speedup vs baseline: 1.1931x; 1.1931x over previous
//
#include <hip/hip_runtime.h>
#include <math.h>

// LDAWordGenerator: z[b,v] = logsumexp_t(log_theta[b,t] + log_phi[t,v])
// Factored: z = mu_v + log( sum_t Ea[b,t] * Ew[t,v] )
//   Ea[t][b] = exp(log_theta[b,t] - g_t),  g_t = max_b log_theta[b,t]
//   Ew[t][v] = exp(w[t,v] + c_t - mu_v),   c_t = g_t - lse_w[t]
//   mu_v = max_t (w[t,v] + c_t)   -> dominant term has Ew=1, Ea >= e^-8: safe.
// B=128, T=128, V=32000.

constexpr int B = 128;
constexpr int T = 128;
constexpr int V = 32000;
constexpr int VC = 128;           // V-columns per block in main kernel
constexpr int KPARTS = 4;         // partial splits per w-row for lse_w
constexpr int PART = V / KPARTS;  // 8000

// ws layout (floats): Ea[T*B] | pm[T*KPARTS] | ps[T*KPARTS] | c[T]
constexpr int WS_EA = 0;
constexpr int WS_PM = T * B;               // 16384
constexpr int WS_PS = WS_PM + T * KPARTS;  // +512
constexpr int WS_C  = WS_PS + T * KPARTS;  // +512

// ---------------- K1: partial online logsumexp over each w row ----------------
__global__ __launch_bounds__(256) void k_lsew_partial(const float* __restrict__ w,
                                                      float* __restrict__ pm,
                                                      float* __restrict__ ps) {
    const int t = blockIdx.x >> 2;
    const int part = blockIdx.x & 3;
    const float* row = w + (size_t)t * V + (size_t)part * PART;

    float m = -INFINITY, s = 0.f;
    for (int v = threadIdx.x; v < PART; v += 256) {
        float x = row[v];
        if (x > m) { s = s * __expf(m - x) + 1.f; m = x; }
        else       { s += __expf(x - m); }
    }
    __shared__ float sm[256], ss[256];
    sm[threadIdx.x] = m; ss[threadIdx.x] = s;
    __syncthreads();
    for (int off = 128; off > 0; off >>= 1) {
        if (threadIdx.x < off) {
            float m1 = sm[threadIdx.x],       s1 = ss[threadIdx.x];
            float m2 = sm[threadIdx.x + off], s2 = ss[threadIdx.x + off];
            float M = fmaxf(m1, m2);
            sm[threadIdx.x] = M;
            ss[threadIdx.x] = s1 * __expf(m1 - M) + s2 * __expf(m2 - M);
        }
        __syncthreads();
    }
    if (threadIdx.x == 0) {
        pm[blockIdx.x] = sm[0];
        ps[blockIdx.x] = ss[0];
    }
}

// ---------------- K2: lse_in, g_t, c_t, Ea — one block, LDS-parallel ----------------
__global__ __launch_bounds__(256) void k_prep(const float* __restrict__ inp,
                                              const float* __restrict__ pm,
                                              const float* __restrict__ ps,
                                              float* __restrict__ c_out,
                                              float* __restrict__ Ea) {
    __shared__ float si[B][T + 1];   // +1 pad: stride 129 == 1 (mod 32) -> conflict-free
    __shared__ float lse_s[B];
    __shared__ float gt[T];
    const int tid = threadIdx.x;

    // stage inputs (B*T = 16384 floats), coalesced
    #pragma unroll
    for (int k = 0; k < (B * T) / 256; ++k) {
        int idx = tid + k * 256;
        si[idx >> 7][idx & 127] = inp[idx];
    }
    __syncthreads();

    // lse_in[b], parallel over rows (threads 0..127)
    if (tid < B) {
        const int b = tid;
        float m = -INFINITY;
        for (int t = 0; t < T; ++t) m = fmaxf(m, si[b][t]);
        float s = 0.f;
        for (int t = 0; t < T; ++t) s += __expf(si[b][t] - m);
        lse_s[b] = m + logf(s);
    }
    __syncthreads();

    // lse_w[t] combine + g_t + c_t (threads 0..127)
    if (tid < T) {
        const int t = tid;
        float M = pm[t * KPARTS];
        for (int p = 1; p < KPARTS; ++p) M = fmaxf(M, pm[t * KPARTS + p]);
        float S = 0.f;
        for (int p = 0; p < KPARTS; ++p) S += ps[t * KPARTS + p] * __expf(pm[t * KPARTS + p] - M);
        float lw = M + logf(S);
        float g = -INFINITY;
        for (int b = 0; b < B; ++b) g = fmaxf(g, si[b][t] - lse_s[b]);
        gt[t] = g;
        c_out[t] = g - lw;
    }
    __syncthreads();

    // Ea[t][b] = exp(si[b][t] - lse_in[b] - g_t); writes coalesced over b
    if (tid < B) {
        const int b = tid;
        const float li = lse_s[b];
        for (int t = 0; t < T; ++t)
            Ea[t * B + b] = __expf(si[b][t] - li - gt[t]);
    }
}

// ---------------- K3: main — mu_v, Ew, fp32 matmul, epilogue ----------------
__global__ __launch_bounds__(256) void k_main(const float* __restrict__ w,
                                              const float* __restrict__ c_in,
                                              const float* __restrict__ Ea_g,
                                              float* __restrict__ out) {
    __shared__ float Ea[T][B];     // 64 KiB  [t][b]
    __shared__ float Ew[T][VC];    // 64 KiB  [t][v] (raw w, transformed in place)
    __shared__ float cs[T];
    __shared__ float mu[VC];
    __shared__ float pmax[2][VC];

    const int tid = threadIdx.x;
    const int vbase = blockIdx.x * VC;

    if (tid < T) cs[tid] = c_in[tid];

    // load Ea: 16384 floats = 4096 float4, 16 per thread, linear
    {
        const float4* src = (const float4*)Ea_g;
        float4* dst = (float4*)&Ea[0][0];
        #pragma unroll
        for (int k = 0; k < 16; ++k) dst[tid + k * 256] = src[tid + k * 256];
    }
    // load w slab [T][VC] raw into Ew: 4096 float4, 16 per thread (32 f4/row)
    {
        #pragma unroll
        for (int k = 0; k < 16; ++k) {
            int idx = tid + k * 256;
            int t = idx >> 5;
            int c4 = idx & 31;
            float4 val = *(const float4*)(w + (size_t)t * V + vbase + c4 * 4);
            *(float4*)&Ew[t][c4 * 4] = val;
        }
    }
    __syncthreads();

    // mu_v = max_t (w[t][v] + c_t): v = tid&127, q = tid>>7 handles a t-half
    {
        const int v = tid & 127, q = tid >> 7;
        float m = -INFINITY;
        for (int t = q * 64; t < q * 64 + 64; ++t) m = fmaxf(m, Ew[t][v] + cs[t]);
        pmax[q][v] = m;
    }
    __syncthreads();
    if (tid < VC) mu[tid] = fmaxf(pmax[0][tid], pmax[1][tid]);
    __syncthreads();

    // Ew in-place: exp(w + c_t - mu_v); 16384 elems, 64 per thread
    {
        #pragma unroll
        for (int k = 0; k < 64; ++k) {
            int idx = tid + k * 256;
            int t = idx >> 7, v = idx & 127;
            Ew[t][v] = __expf(Ew[t][v] + cs[t] - mu[v]);
        }
    }
    __syncthreads();

    // matmul: thread tile 8b x 8v. tv = tid&15 -> v0 = tv*8; tb = tid>>4 -> b0 = tb*8
    const int tv = tid & 15, tb = tid >> 4;
    const int v0 = tv * 8, b0 = tb * 8;

    float acc[8][8];
    #pragma unroll
    for (int i = 0; i < 8; ++i)
        #pragma unroll
        for (int j = 0; j < 8; ++j) acc[i][j] = 0.f;

    #pragma unroll 2
    for (int t = 0; t < T; ++t) {
        float4 ew0 = *(float4*)&Ew[t][v0];
        float4 ew1 = *(float4*)&Ew[t][v0 + 4];
        float4 ea0 = *(float4*)&Ea[t][b0];
        float4 ea1 = *(float4*)&Ea[t][b0 + 4];
        float ea[8] = {ea0.x, ea0.y, ea0.z, ea0.w, ea1.x, ea1.y, ea1.z, ea1.w};
        float ewv[8] = {ew0.x, ew0.y, ew0.z, ew0.w, ew1.x, ew1.y, ew1.z, ew1.w};
        #pragma unroll
        for (int i = 0; i < 8; ++i)
            #pragma unroll
            for (int j = 0; j < 8; ++j)
                acc[i][j] = fmaf(ea[i], ewv[j], acc[i][j]);
    }

    // epilogue: z = mu_v + log(P)
    #pragma unroll
    for (int i = 0; i < 8; ++i) {
        const int b = b0 + i;
        float4 z0, z1;
        z0.x = mu[v0 + 0] + __logf(acc[i][0]);
        z0.y = mu[v0 + 1] + __logf(acc[i][1]);
        z0.z = mu[v0 + 2] + __logf(acc[i][2]);
        z0.w = mu[v0 + 3] + __logf(acc[i][3]);
        z1.x = mu[v0 + 4] + __logf(acc[i][4]);
        z1.y = mu[v0 + 5] + __logf(acc[i][5]);
        z1.z = mu[v0 + 6] + __logf(acc[i][6]);
        z1.w = mu[v0 + 7] + __logf(acc[i][7]);
        float* dst = out + (size_t)b * V + vbase + v0;
        *(float4*)dst = z0;
        *(float4*)(dst + 4) = z1;
    }
}

extern "C" void kernel_launch(void* const* d_in, const int* in_sizes, int n_in,
                              void* d_out, int out_size, void* d_ws, size_t ws_size,
                              hipStream_t stream) {
    const float* inp = (const float*)d_in[0];  // (B, T) f32
    const float* w   = (const float*)d_in[1];  // (T, V) f32
    float* out = (float*)d_out;                // (B, V) f32
    float* ws  = (float*)d_ws;

    float* Ea = ws + WS_EA;
    float* pm = ws + WS_PM;
    float* ps = ws + WS_PS;
    float* c  = ws + WS_C;

    k_lsew_partial<<<dim3(T * KPARTS), dim3(256), 0, stream>>>(w, pm, ps);
    k_prep<<<dim3(1), dim3(256), 0, stream>>>(inp, pm, ps, c, Ea);
    k_main<<<dim3(V / VC), dim3(256), 0, stream>>>(w, c, Ea, out);
}

// Round 3
// 46.366 us; speedup vs baseline: 1.6030x; 1.3436x over previous
//
#include <hip/hip_runtime.h>
#include <math.h>

// LDAWordGenerator: z[b,v] = logsumexp_t(log_theta[b,t] + log_phi[t,v])
// Factored: z = mu_v + log( sum_t Ea[b,t] * Ew[t,v] )
//   Ea[b][t] = exp(log_theta[b,t] - g_t),  g_t = max_b log_theta[b,t]
//   Ew[t][v] = exp(w[t,v] + c_t - mu_v),   c_t = g_t - lse_w[t]
//   mu_v = max_t (w[t,v] + c_t)  -> dominant term has Ew=1, Ea >= e^-spread: safe.
// Matmul over t done with bf16 MFMA (Ea,Ew in (0,1]; log() compresses the
// 0.4% relative rounding to ~4e-3 absolute on z).
// B=128, T=128, V=32000.

constexpr int B = 128;
constexpr int T = 128;
constexpr int V = 32000;
constexpr int VC = 128;           // V-columns per k_main block
constexpr int KPARTS = 4;
constexpr int PART = V / KPARTS;  // 8000

// ws layout (32-bit words): EaPacked[128*64] | pm[512] | ps[512] | c[128]
constexpr int WS_EA = 0;                   // 8192 u32 (swizzled packed bf16 pairs)
constexpr int WS_PM = 8192;
constexpr int WS_PS = WS_PM + T * KPARTS;
constexpr int WS_C  = WS_PS + T * KPARTS;

typedef __attribute__((ext_vector_type(8))) short bf16x8;
typedef __attribute__((ext_vector_type(4))) float f32x4;

__device__ inline unsigned short f2bf(float f) {
    union { float f; unsigned u; } x; x.f = f;
    unsigned u = x.u + 0x7fff + ((x.u >> 16) & 1);   // round-to-nearest-even
    return (unsigned short)(u >> 16);
}

// ---------------- K1: partial online logsumexp over each w row ----------------
__global__ __launch_bounds__(256) void k_lsew_partial(const float* __restrict__ w,
                                                      float* __restrict__ pm,
                                                      float* __restrict__ ps) {
    const int t = blockIdx.x >> 2;
    const int part = blockIdx.x & 3;
    const float4* row = (const float4*)(w + (size_t)t * V + (size_t)part * PART);

    float m = -INFINITY, s = 0.f;
    for (int i = threadIdx.x; i < PART / 4; i += 256) {
        float4 x4 = row[i];
        float xs[4] = {x4.x, x4.y, x4.z, x4.w};
        #pragma unroll
        for (int j = 0; j < 4; ++j) {
            float x = xs[j];
            if (x > m) { s = s * __expf(m - x) + 1.f; m = x; }
            else       { s += __expf(x - m); }
        }
    }
    __shared__ float sm[256], ss[256];
    sm[threadIdx.x] = m; ss[threadIdx.x] = s;
    __syncthreads();
    for (int off = 128; off > 0; off >>= 1) {
        if (threadIdx.x < off) {
            float m1 = sm[threadIdx.x],       s1 = ss[threadIdx.x];
            float m2 = sm[threadIdx.x + off], s2 = ss[threadIdx.x + off];
            float M = fmaxf(m1, m2);
            sm[threadIdx.x] = M;
            ss[threadIdx.x] = s1 * __expf(m1 - M) + s2 * __expf(m2 - M);
        }
        __syncthreads();
    }
    if (threadIdx.x == 0) {
        pm[blockIdx.x] = sm[0];
        ps[blockIdx.x] = ss[0];
    }
}

// ---------------- K2: lse_in, g_t, c_t, Ea(bf16, pre-swizzled) ----------------
__global__ __launch_bounds__(256) void k_prep(const float* __restrict__ inp,
                                              const float* __restrict__ pm,
                                              const float* __restrict__ ps,
                                              float* __restrict__ c_out,
                                              unsigned* __restrict__ Ea) {
    __shared__ float si[B][T + 1];   // stride 129 -> conflict-free both axes
    __shared__ float lse_s[B];
    __shared__ float gt[T];
    const int tid = threadIdx.x;

    // stage inputs coalesced (4096 float4)
    #pragma unroll
    for (int k = 0; k < 16; ++k) {
        int i4 = tid + k * 256;
        float4 x = ((const float4*)inp)[i4];
        int r = i4 >> 5, c = (i4 & 31) * 4;
        si[r][c] = x.x; si[r][c + 1] = x.y; si[r][c + 2] = x.z; si[r][c + 3] = x.w;
    }
    __syncthreads();

    if (tid < B) {   // lse_in[b]
        const int b = tid;
        float m = -INFINITY;
        for (int t = 0; t < T; ++t) m = fmaxf(m, si[b][t]);
        float s = 0.f;
        for (int t = 0; t < T; ++t) s += __expf(si[b][t] - m);
        lse_s[b] = m + logf(s);
    }
    __syncthreads();

    if (tid < T) {   // lse_w combine + g_t + c_t
        const int t = tid;
        float M = pm[t * KPARTS];
        for (int p = 1; p < KPARTS; ++p) M = fmaxf(M, pm[t * KPARTS + p]);
        float S = 0.f;
        for (int p = 0; p < KPARTS; ++p) S += ps[t * KPARTS + p] * __expf(pm[t * KPARTS + p] - M);
        float lw = M + logf(S);
        float g = -INFINITY;
        for (int b = 0; b < B; ++b) g = fmaxf(g, si[b][t] - lse_s[b]);
        gt[t] = g;
        c_out[t] = g - lw;
    }
    __syncthreads();

    // Ea packed bf16 pairs, layout: word[b*64 + (tp ^ ((b&7)<<2))] = {t=2tp, t=2tp+1}
    if (tid < B) {
        const int b = tid;
        const float li = lse_s[b];
        for (int tp = 0; tp < 64; ++tp) {
            float e0 = __expf(si[b][2 * tp]     - li - gt[2 * tp]);
            float e1 = __expf(si[b][2 * tp + 1] - li - gt[2 * tp + 1]);
            Ea[b * 64 + (tp ^ ((b & 7) << 2))] =
                (unsigned)f2bf(e0) | ((unsigned)f2bf(e1) << 16);
        }
    }
}

// ---------------- K3: mu, Ew(bf16 transposed), MFMA matmul, epilogue ----------------
__global__ __launch_bounds__(256) void k_main(const float* __restrict__ w,
                                              const float* __restrict__ c_in,
                                              const unsigned* __restrict__ Ea_g,
                                              float* __restrict__ out) {
    __shared__ unsigned EaL[B * 64];   // 32 KiB, swizzled [b][tpair]
    __shared__ unsigned EwL[VC * 64];  // 32 KiB, swizzled [v][tpair]
    __shared__ float cs[T];
    __shared__ float mu[VC];
    __shared__ float pmH[2][VC];

    const int tid = threadIdx.x;
    const int vbase = blockIdx.x * VC;

    if (tid < T) cs[tid] = c_in[tid];

    // stage Ea (already swizzled in ws): linear 32 KiB copy
    {
        const float4* src = (const float4*)Ea_g;
        float4* dst = (float4*)EaL;
        #pragma unroll
        for (int k = 0; k < 8; ++k) dst[tid + k * 256] = src[tid + k * 256];
    }
    __syncthreads();   // cs ready

    // mu_v = max_t (w[t][v] + c_t): lanes span v (coalesced), q = t-half
    {
        const int v = tid & 127, q = tid >> 7;
        const float* col = w + vbase + v;
        float m = -INFINITY;
        for (int t = q * 64; t < q * 64 + 64; ++t)
            m = fmaxf(m, col[(size_t)t * V] + cs[t]);
        pmH[q][v] = m;
    }
    __syncthreads();
    if (tid < VC) mu[tid] = fmaxf(pmH[0][tid], pmH[1][tid]);
    __syncthreads();

    // transform: Ew[v][t] = bf16(exp(w[t][v] + c_t - mu_v)), transposed + swizzled.
    // lanes span v (global reads coalesced, L2-warm from mu pass)
    #pragma unroll 8
    for (int k = 0; k < 32; ++k) {
        int e = tid + k * 256;
        int v = e & 127, tp = e >> 7;
        float w0 = w[(size_t)(2 * tp) * V + vbase + v];
        float w1 = w[(size_t)(2 * tp + 1) * V + vbase + v];
        float m_ = mu[v];
        float e0 = __expf(w0 + cs[2 * tp] - m_);
        float e1 = __expf(w1 + cs[2 * tp + 1] - m_);
        EwL[v * 64 + (tp ^ ((v & 7) << 2))] =
            (unsigned)f2bf(e0) | ((unsigned)f2bf(e1) << 16);
    }
    __syncthreads();

    // MFMA: C[b][v] = sum_t Ea[b][t]*Ew^T[v][t]. 4 waves, each 64b x 64v.
    const int lane = tid & 63;
    const int wave = tid >> 6;
    const int wb = (wave >> 1) * 64;
    const int wv = (wave & 1) * 64;
    const int r = lane & 15;
    const int g = lane >> 4;

    f32x4 acc[4][4];
    #pragma unroll
    for (int m = 0; m < 4; ++m)
        #pragma unroll
        for (int n = 0; n < 4; ++n) acc[m][n] = (f32x4){0.f, 0.f, 0.f, 0.f};

    #pragma unroll
    for (int kk = 0; kk < 4; ++kk) {
        bf16x8 af[4], bfr[4];
        #pragma unroll
        for (int m = 0; m < 4; ++m) {
            int bb = wb + m * 16 + r;
            int tb = (kk * 64 + g * 16) ^ ((bb & 7) << 4);
            af[m] = *(const bf16x8*)((const char*)EaL + bb * 256 + tb);
        }
        #pragma unroll
        for (int n = 0; n < 4; ++n) {
            int vv = wv + n * 16 + r;
            int tb = (kk * 64 + g * 16) ^ ((vv & 7) << 4);
            bfr[n] = *(const bf16x8*)((const char*)EwL + vv * 256 + tb);
        }
        #pragma unroll
        for (int m = 0; m < 4; ++m)
            #pragma unroll
            for (int n = 0; n < 4; ++n)
                acc[m][n] = __builtin_amdgcn_mfma_f32_16x16x32_bf16(af[m], bfr[n], acc[m][n], 0, 0, 0);
    }

    // epilogue: z = mu_v + log(P). C layout: col=lane&15, row=g*4+j.
    #pragma unroll
    for (int m = 0; m < 4; ++m) {
        int bb = wb + m * 16 + g * 4;
        #pragma unroll
        for (int n = 0; n < 4; ++n) {
            float muv = mu[wv + n * 16 + r];
            size_t col = (size_t)(vbase + wv + n * 16 + r);
            #pragma unroll
            for (int j = 0; j < 4; ++j)
                out[(size_t)(bb + j) * V + col] = muv + __logf(acc[m][n][j]);
        }
    }
}

extern "C" void kernel_launch(void* const* d_in, const int* in_sizes, int n_in,
                              void* d_out, int out_size, void* d_ws, size_t ws_size,
                              hipStream_t stream) {
    const float* inp = (const float*)d_in[0];  // (B, T) f32
    const float* w   = (const float*)d_in[1];  // (T, V) f32
    float* out = (float*)d_out;                // (B, V) f32
    unsigned* ws = (unsigned*)d_ws;

    unsigned* Ea = ws + WS_EA;
    float* pm = (float*)(ws + WS_PM);
    float* ps = (float*)(ws + WS_PS);
    float* c  = (float*)(ws + WS_C);

    k_lsew_partial<<<dim3(T * KPARTS), dim3(256), 0, stream>>>(w, pm, ps);
    k_prep<<<dim3(1), dim3(256), 0, stream>>>(inp, pm, ps, c, Ea);
    k_main<<<dim3(V / VC), dim3(256), 0, stream>>>(w, c, Ea, out);
}

// Round 4
// 35.934 us; speedup vs baseline: 2.0683x; 1.2903x over previous
//
#include <hip/hip_runtime.h>
#include <math.h>

// LDAWordGenerator: z[b,v] = logsumexp_t(log_theta[b,t] + log_phi[t,v])
// Factored: z = mu_v + log( sum_t Ea[b,t] * Ew[t,v] )
//   Ea[b][t] = exp(log_theta[b,t] - g_t),  g_t = max_b log_theta[b,t]
//   Ew[t][v] = exp(w[t,v] + c_t - mu_v),   c_t = g_t - lse_w[t]
//   mu_v = max_t (w[t,v] + c_t)  -> dominant term has Ew=1, Ea >= e^-spread: safe.
// Matmul over t via bf16 MFMA (Ea,Ew in (0,1]; log() compresses rounding).
// B=128, T=128, V=32000.

constexpr int B = 128;
constexpr int T = 128;
constexpr int V = 32000;
constexpr int VC = 64;            // V-columns per k_main block
constexpr int KPARTS = 4;
constexpr int PART = V / KPARTS;  // 8000

// ws layout (32-bit words): EaPacked[128*64] | pm[512] | ps[512] | c[128]
constexpr int WS_EA = 0;                   // 8192 u32 (grp-swizzled packed bf16 pairs)
constexpr int WS_PM = 8192;
constexpr int WS_PS = WS_PM + T * KPARTS;
constexpr int WS_C  = WS_PS + T * KPARTS;

typedef __attribute__((ext_vector_type(8))) short bf16x8;
typedef __attribute__((ext_vector_type(4))) float f32x4;
typedef __attribute__((ext_vector_type(4))) unsigned u32x4;

__device__ inline unsigned short f2bf(float f) {
    union { float f; unsigned u; } x; x.f = f;
    unsigned u = x.u + 0x7fff + ((x.u >> 16) & 1);   // round-to-nearest-even
    return (unsigned short)(u >> 16);
}

// Swizzled word index within a 64-word (256B) row: tp-group grp = tp>>2 is
// XOR'd with (row&15); fragment reads pull 16B at group (kk*4+g)^(row&15).
__device__ inline int swz_word(int row, int tp) {
    return (((tp >> 2) ^ (row & 15)) << 2) | (tp & 3);
}

// ---------------- K1: partial online logsumexp over each w row ----------------
__global__ __launch_bounds__(256) void k_lsew_partial(const float* __restrict__ w,
                                                      float* __restrict__ pm,
                                                      float* __restrict__ ps) {
    const int t = blockIdx.x >> 2;
    const int part = blockIdx.x & 3;
    const float4* row = (const float4*)(w + (size_t)t * V + (size_t)part * PART);

    float m = -INFINITY, s = 0.f;
    for (int i = threadIdx.x; i < PART / 4; i += 256) {
        float4 x4 = row[i];
        float xs[4] = {x4.x, x4.y, x4.z, x4.w};
        #pragma unroll
        for (int j = 0; j < 4; ++j) {
            float x = xs[j];
            if (x > m) { s = s * __expf(m - x) + 1.f; m = x; }
            else       { s += __expf(x - m); }
        }
    }
    __shared__ float sm[256], ss[256];
    sm[threadIdx.x] = m; ss[threadIdx.x] = s;
    __syncthreads();
    for (int off = 128; off > 0; off >>= 1) {
        if (threadIdx.x < off) {
            float m1 = sm[threadIdx.x],       s1 = ss[threadIdx.x];
            float m2 = sm[threadIdx.x + off], s2 = ss[threadIdx.x + off];
            float M = fmaxf(m1, m2);
            sm[threadIdx.x] = M;
            ss[threadIdx.x] = s1 * __expf(m1 - M) + s2 * __expf(m2 - M);
        }
        __syncthreads();
    }
    if (threadIdx.x == 0) {
        pm[blockIdx.x] = sm[0];
        ps[blockIdx.x] = ss[0];
    }
}

// ---------------- K2: lse_in, g_t, c_t, Ea(bf16, pre-swizzled) ----------------
__global__ __launch_bounds__(256) void k_prep(const float* __restrict__ inp,
                                              const float* __restrict__ pm,
                                              const float* __restrict__ ps,
                                              float* __restrict__ c_out,
                                              unsigned* __restrict__ Ea) {
    __shared__ float si[B][T + 1];   // stride 129 -> conflict-free both axes
    __shared__ float lse_s[B];
    __shared__ float gt[T];
    const int tid = threadIdx.x;

    // stage inputs coalesced (4096 float4)
    #pragma unroll
    for (int k = 0; k < 16; ++k) {
        int i4 = tid + k * 256;
        float4 x = ((const float4*)inp)[i4];
        int r = i4 >> 5, c = (i4 & 31) * 4;
        si[r][c] = x.x; si[r][c + 1] = x.y; si[r][c + 2] = x.z; si[r][c + 3] = x.w;
    }
    __syncthreads();

    if (tid < B) {   // lse_in[b]
        const int b = tid;
        float m = -INFINITY;
        for (int t = 0; t < T; ++t) m = fmaxf(m, si[b][t]);
        float s = 0.f;
        for (int t = 0; t < T; ++t) s += __expf(si[b][t] - m);
        lse_s[b] = m + logf(s);
    }
    __syncthreads();

    if (tid < T) {   // lse_w combine + g_t + c_t
        const int t = tid;
        float M = pm[t * KPARTS];
        for (int p = 1; p < KPARTS; ++p) M = fmaxf(M, pm[t * KPARTS + p]);
        float S = 0.f;
        for (int p = 0; p < KPARTS; ++p) S += ps[t * KPARTS + p] * __expf(pm[t * KPARTS + p] - M);
        float lw = M + logf(S);
        float g = -INFINITY;
        for (int b = 0; b < B; ++b) g = fmaxf(g, si[b][t] - lse_s[b]);
        gt[t] = g;
        c_out[t] = g - lw;
    }
    __syncthreads();

    // Ea packed bf16 pairs, grp-swizzled: word[b*64 + swz_word(b, tp)]
    if (tid < B) {
        const int b = tid;
        const float li = lse_s[b];
        for (int tp = 0; tp < 64; ++tp) {
            float e0 = __expf(si[b][2 * tp]     - li - gt[2 * tp]);
            float e1 = __expf(si[b][2 * tp + 1] - li - gt[2 * tp + 1]);
            Ea[b * 64 + swz_word(b, tp)] =
                (unsigned)f2bf(e0) | ((unsigned)f2bf(e1) << 16);
        }
    }
}

// ---------------- K3: mu, Ew(bf16 transposed), MFMA matmul, epilogue ----------------
__global__ __launch_bounds__(256) void k_main(const float* __restrict__ w,
                                              const float* __restrict__ c_in,
                                              const unsigned* __restrict__ Ea_g,
                                              float* __restrict__ out) {
    __shared__ unsigned EaL[B * 64];    // 32 KiB, swizzled [b][tp]
    __shared__ unsigned EwL[VC * 64];   // 16 KiB, swizzled [v][tp]
    __shared__ float cs[T];
    __shared__ float mu[VC];
    __shared__ float pmH[4][VC];

    const int tid = threadIdx.x;
    const int vbase = blockIdx.x * VC;

    if (tid < T) cs[tid] = c_in[tid];

    // stage Ea (already swizzled in ws): linear 32 KiB copy
    {
        const float4* src = (const float4*)Ea_g;
        float4* dst = (float4*)EaL;
        #pragma unroll
        for (int k = 0; k < 8; ++k) dst[tid + k * 256] = src[tid + k * 256];
    }
    __syncthreads();   // cs ready

    // mu_v = max_t (w[t][v] + c_t): lanes span v (coalesced 256B), q = t-quarter
    const int v = tid & 63, q = tid >> 6;
    {
        const float* col = w + vbase + v;
        float m = -INFINITY;
        for (int t = q * 32; t < q * 32 + 32; ++t)
            m = fmaxf(m, col[(size_t)t * V] + cs[t]);
        pmH[q][v] = m;
    }
    __syncthreads();
    if (tid < VC)
        mu[tid] = fmaxf(fmaxf(pmH[0][tid], pmH[1][tid]), fmaxf(pmH[2][tid], pmH[3][tid]));
    __syncthreads();

    // transform: Ew[v][t] = bf16(exp(w[t][v] + c_t - mu_v)), transposed, swizzled.
    // thread (v, q) owns tp-groups q*4..q*4+3; 16B write per group.
    {
        const float m_ = mu[v];
        #pragma unroll
        for (int gi = 0; gi < 4; ++gi) {
            const int g2 = q * 4 + gi;
            unsigned pk[4];
            #pragma unroll
            for (int i = 0; i < 4; ++i) {
                int tp = g2 * 4 + i;
                float w0 = w[(size_t)(2 * tp) * V + vbase + v];
                float w1 = w[(size_t)(2 * tp + 1) * V + vbase + v];
                float e0 = __expf(w0 + cs[2 * tp] - m_);
                float e1 = __expf(w1 + cs[2 * tp + 1] - m_);
                pk[i] = (unsigned)f2bf(e0) | ((unsigned)f2bf(e1) << 16);
            }
            u32x4* dst = (u32x4*)&EwL[v * 64 + ((g2 ^ (v & 15)) << 2)];
            *dst = (u32x4){pk[0], pk[1], pk[2], pk[3]};
        }
    }
    __syncthreads();

    // MFMA: C[b][v] = sum_t Ea[b][t]*Ew^T[v][t]. 4 waves, each 64b x 32v.
    const int lane = tid & 63;
    const int wave = tid >> 6;
    const int wb = (wave >> 1) * 64;
    const int wv = (wave & 1) * 32;
    const int r = lane & 15;
    const int g = lane >> 4;

    f32x4 acc[4][2];
    #pragma unroll
    for (int m = 0; m < 4; ++m)
        #pragma unroll
        for (int n = 0; n < 2; ++n) acc[m][n] = (f32x4){0.f, 0.f, 0.f, 0.f};

    #pragma unroll
    for (int kk = 0; kk < 4; ++kk) {
        const int grp = kk * 4 + g;
        bf16x8 af[4], bfr[2];
        #pragma unroll
        for (int m = 0; m < 4; ++m) {
            int bb = wb + m * 16 + r;
            af[m] = *(const bf16x8*)((const char*)EaL + bb * 256 + ((grp ^ (bb & 15)) << 4));
        }
        #pragma unroll
        for (int n = 0; n < 2; ++n) {
            int vv = wv + n * 16 + r;
            bfr[n] = *(const bf16x8*)((const char*)EwL + vv * 256 + ((grp ^ (vv & 15)) << 4));
        }
        #pragma unroll
        for (int m = 0; m < 4; ++m)
            #pragma unroll
            for (int n = 0; n < 2; ++n)
                acc[m][n] = __builtin_amdgcn_mfma_f32_16x16x32_bf16(af[m], bfr[n], acc[m][n], 0, 0, 0);
    }

    // epilogue: z = mu_v + log(P). C layout: col=lane&15, row=g*4+j.
    #pragma unroll
    for (int m = 0; m < 4; ++m) {
        int bb = wb + m * 16 + g * 4;
        #pragma unroll
        for (int n = 0; n < 2; ++n) {
            float muv = mu[wv + n * 16 + r];
            size_t col = (size_t)(vbase + wv + n * 16 + r);
            #pragma unroll
            for (int j = 0; j < 4; ++j)
                out[(size_t)(bb + j) * V + col] = muv + __logf(acc[m][n][j]);
        }
    }
}

extern "C" void kernel_launch(void* const* d_in, const int* in_sizes, int n_in,
                              void* d_out, int out_size, void* d_ws, size_t ws_size,
                              hipStream_t stream) {
    const float* inp = (const float*)d_in[0];  // (B, T) f32
    const float* w   = (const float*)d_in[1];  // (T, V) f32
    float* out = (float*)d_out;                // (B, V) f32
    unsigned* ws = (unsigned*)d_ws;

    unsigned* Ea = ws + WS_EA;
    float* pm = (float*)(ws + WS_PM);
    float* ps = (float*)(ws + WS_PS);
    float* c  = (float*)(ws + WS_C);

    k_lsew_partial<<<dim3(T * KPARTS), dim3(256), 0, stream>>>(w, pm, ps);
    k_prep<<<dim3(1), dim3(256), 0, stream>>>(inp, pm, ps, c, Ea);
    k_main<<<dim3(V / VC), dim3(256), 0, stream>>>(w, c, Ea, out);
}

// Round 5
// 34.637 us; speedup vs baseline: 2.1457x; 1.0374x over previous
//
#include <hip/hip_runtime.h>
#include <math.h>

// LDAWordGenerator: z[b,v] = logsumexp_t(log_theta[b,t] + log_phi[t,v])
// Factored: z = mu_v + log( sum_t Ea[b,t] * Ew[t,v] )
//   Ea[b][t] = exp(log_theta[b,t] - g_t),  g_t = max_b log_theta[b,t]
//   Ew[t][v] = exp(w[t,v] + c_t - mu_v),   c_t = g_t - lse_w[t]
//   mu_v = max_t (w[t,v] + c_t)  -> dominant term has Ew=1, Ea >= e^-spread: safe.
// Matmul over t via bf16 MFMA. B=128, T=128, V=32000.

constexpr int B = 128;
constexpr int T = 128;
constexpr int V = 32000;
constexpr int VC = 64;            // V-columns per k_main block
constexpr int KPARTS = 4;
constexpr int PART = V / KPARTS;  // 8000

// ws layout (32-bit words): EaPacked[8192] | pm[512] | ps[512] | gt[128]
constexpr int WS_EA = 0;
constexpr int WS_PM = 8192;
constexpr int WS_PS = WS_PM + T * KPARTS;
constexpr int WS_GT = WS_PS + T * KPARTS;

typedef __attribute__((ext_vector_type(8))) short bf16x8;
typedef __attribute__((ext_vector_type(4))) float f32x4;
typedef __attribute__((ext_vector_type(4))) unsigned u32x4;

__device__ inline unsigned short f2bf(float f) {
    union { float f; unsigned u; } x; x.f = f;
    unsigned u = x.u + 0x7fff + ((x.u >> 16) & 1);   // round-to-nearest-even
    return (unsigned short)(u >> 16);
}

// Swizzled word index within a 64-word (256B) row: 16B-group (tp>>2) XOR (row&15).
__device__ inline int swz_word(int row, int tp) {
    return (((tp >> 2) ^ (row & 15)) << 2) | (tp & 3);
}

// ---------------- KA: block 0 = prep (lse_in, g_t, Ea, gt); blocks 1..512 = lse_w partials ----
__global__ __launch_bounds__(256) void k_stage1(const float* __restrict__ inp,
                                                const float* __restrict__ w,
                                                float* __restrict__ pm,
                                                float* __restrict__ ps,
                                                float* __restrict__ gt_out,
                                                unsigned* __restrict__ Ea) {
    __shared__ float sh[B * (T + 1)];   // prep: si[b][t] at sh[b*129+t], lse_in[b] at col 128
    __shared__ float gts[T];
    const int tid = threadIdx.x;

    if (blockIdx.x != 0) {
        // ---- lse_w partial over one quarter-row of w (branchless online) ----
        const int bid = blockIdx.x - 1;
        const int t = bid >> 2;
        const int part = bid & 3;
        const float4* row = (const float4*)(w + (size_t)t * V + (size_t)part * PART);

        float m = -INFINITY, s = 0.f;
        for (int i = tid; i < PART / 4; i += 256) {
            float4 x4 = row[i];
            float xs[4] = {x4.x, x4.y, x4.z, x4.w};
            #pragma unroll
            for (int j = 0; j < 4; ++j) {
                float x = xs[j];
                float mn = fmaxf(m, x);
                s = s * __expf(m - mn) + __expf(x - mn);
                m = mn;
            }
        }
        float* sm = sh;         // [256]
        float* ss = sh + 256;   // [256]
        sm[tid] = m; ss[tid] = s;
        __syncthreads();
        for (int off = 128; off > 0; off >>= 1) {
            if (tid < off) {
                float m1 = sm[tid],       s1 = ss[tid];
                float m2 = sm[tid + off], s2 = ss[tid + off];
                float M = fmaxf(m1, m2);
                sm[tid] = M;
                ss[tid] = s1 * __expf(m1 - M) + s2 * __expf(m2 - M);
            }
            __syncthreads();
        }
        if (tid == 0) { pm[bid] = sm[0]; ps[bid] = ss[0]; }
        return;
    }

    // ---- prep block ----
    // stage inputs coalesced (4096 float4)
    #pragma unroll
    for (int k = 0; k < 16; ++k) {
        int i4 = tid + k * 256;
        float4 x = ((const float4*)inp)[i4];
        int r = i4 >> 5, c = (i4 & 31) * 4;
        float* dst = &sh[r * 129 + c];
        dst[0] = x.x; dst[1] = x.y; dst[2] = x.z; dst[3] = x.w;
    }
    __syncthreads();

    if (tid < B) {   // lse_in[b] -> pad column 128
        const int b = tid;
        const float* row = &sh[b * 129];
        float m = -INFINITY;
        for (int t = 0; t < T; ++t) m = fmaxf(m, row[t]);
        float s = 0.f;
        for (int t = 0; t < T; ++t) s += __expf(row[t] - m);
        sh[b * 129 + 128] = m + logf(s);
    }
    __syncthreads();

    if (tid < T) {   // g_t = max_b(inp[b][t] - lse_in[b])
        const int t = tid;
        float g = -INFINITY;
        for (int b = 0; b < B; ++b) g = fmaxf(g, sh[b * 129 + t] - sh[b * 129 + 128]);
        gts[t] = g;
        gt_out[t] = g;
    }
    __syncthreads();

    if (tid < B) {   // pack Ea bf16 pairs in place into row b, cols 0..63 (swizzled)
        const int b = tid;
        const float li = sh[b * 129 + 128];
        unsigned pk[64];
        #pragma unroll
        for (int tp = 0; tp < 64; ++tp) {
            float e0 = __expf(sh[b * 129 + 2 * tp]     - li - gts[2 * tp]);
            float e1 = __expf(sh[b * 129 + 2 * tp + 1] - li - gts[2 * tp + 1]);
            pk[tp] = (unsigned)f2bf(e0) | ((unsigned)f2bf(e1) << 16);
        }
        unsigned* row = (unsigned*)&sh[b * 129];
        #pragma unroll
        for (int tp = 0; tp < 64; ++tp) row[swz_word(b, tp)] = pk[tp];
    }
    __syncthreads();

    // coalesced copy-out: 8192 words, 32 per thread
    #pragma unroll
    for (int k = 0; k < 32; ++k) {
        int d = tid + k * 256;
        int b = d >> 6, wsw = d & 63;
        Ea[d] = ((unsigned*)&sh[b * 129])[wsw];
    }
}

// ---------------- KB: cs combine, mu, Ew(bf16 transposed), MFMA, epilogue ----------------
__global__ __launch_bounds__(256) void k_main(const float* __restrict__ w,
                                              const float* __restrict__ pm,
                                              const float* __restrict__ ps,
                                              const float* __restrict__ gt,
                                              const unsigned* __restrict__ Ea_g,
                                              float* __restrict__ out) {
    __shared__ unsigned EaL[B * 64];    // 32 KiB, swizzled [b][tp]
    __shared__ unsigned EwL[VC * 64];   // 16 KiB, swizzled [v][tp]
    __shared__ float cs[T];
    __shared__ float mu[VC];
    __shared__ float pmH[4][VC];

    const int tid = threadIdx.x;
    const int vbase = blockIdx.x * VC;

    if (tid < T) {   // c_t = g_t - lse_w[t]
        const int t = tid;
        float M = pm[t * KPARTS];
        #pragma unroll
        for (int p = 1; p < KPARTS; ++p) M = fmaxf(M, pm[t * KPARTS + p]);
        float S = 0.f;
        #pragma unroll
        for (int p = 0; p < KPARTS; ++p) S += ps[t * KPARTS + p] * __expf(pm[t * KPARTS + p] - M);
        cs[t] = gt[t] - (M + logf(S));
    }

    // stage Ea (pre-swizzled in ws): linear 32 KiB copy
    {
        const float4* src = (const float4*)Ea_g;
        float4* dst = (float4*)EaL;
        #pragma unroll
        for (int k = 0; k < 8; ++k) dst[tid + k * 256] = src[tid + k * 256];
    }
    __syncthreads();   // cs ready

    // mu_v = max_t (w[t][v] + c_t): lanes span v (coalesced 256B), q = t-quarter
    const int v = tid & 63, q = tid >> 6;
    {
        const float* col = w + vbase + v;
        float m = -INFINITY;
        #pragma unroll 8
        for (int t = q * 32; t < q * 32 + 32; ++t)
            m = fmaxf(m, col[(size_t)t * V] + cs[t]);
        pmH[q][v] = m;
    }
    __syncthreads();
    if (tid < VC)
        mu[tid] = fmaxf(fmaxf(pmH[0][tid], pmH[1][tid]), fmaxf(pmH[2][tid], pmH[3][tid]));
    __syncthreads();

    // transform: Ew[v][t] = bf16(exp(w[t][v] + c_t - mu_v)), transposed + swizzled.
    {
        const float m_ = mu[v];
        #pragma unroll
        for (int gi = 0; gi < 4; ++gi) {
            const int g2 = q * 4 + gi;
            unsigned pk[4];
            #pragma unroll
            for (int i = 0; i < 4; ++i) {
                int tp = g2 * 4 + i;
                float w0 = w[(size_t)(2 * tp) * V + vbase + v];
                float w1 = w[(size_t)(2 * tp + 1) * V + vbase + v];
                float e0 = __expf(w0 + cs[2 * tp] - m_);
                float e1 = __expf(w1 + cs[2 * tp + 1] - m_);
                pk[i] = (unsigned)f2bf(e0) | ((unsigned)f2bf(e1) << 16);
            }
            u32x4* dst = (u32x4*)&EwL[v * 64 + ((g2 ^ (v & 15)) << 2)];
            *dst = (u32x4){pk[0], pk[1], pk[2], pk[3]};
        }
    }
    __syncthreads();

    // MFMA: C[b][v] = sum_t Ea[b][t]*Ew^T[v][t]. 4 waves, each 64b x 32v.
    const int lane = tid & 63;
    const int wave = tid >> 6;
    const int wb = (wave >> 1) * 64;
    const int wv = (wave & 1) * 32;
    const int r = lane & 15;
    const int g = lane >> 4;

    f32x4 acc[4][2];
    #pragma unroll
    for (int m = 0; m < 4; ++m)
        #pragma unroll
        for (int n = 0; n < 2; ++n) acc[m][n] = (f32x4){0.f, 0.f, 0.f, 0.f};

    #pragma unroll
    for (int kk = 0; kk < 4; ++kk) {
        const int grp = kk * 4 + g;
        bf16x8 af[4], bfr[2];
        #pragma unroll
        for (int m = 0; m < 4; ++m) {
            int bb = wb + m * 16 + r;
            af[m] = *(const bf16x8*)((const char*)EaL + bb * 256 + ((grp ^ (bb & 15)) << 4));
        }
        #pragma unroll
        for (int n = 0; n < 2; ++n) {
            int vv = wv + n * 16 + r;
            bfr[n] = *(const bf16x8*)((const char*)EwL + vv * 256 + ((grp ^ (vv & 15)) << 4));
        }
        #pragma unroll
        for (int m = 0; m < 4; ++m)
            #pragma unroll
            for (int n = 0; n < 2; ++n)
                acc[m][n] = __builtin_amdgcn_mfma_f32_16x16x32_bf16(af[m], bfr[n], acc[m][n], 0, 0, 0);
    }

    // epilogue: z = mu_v + log(P). C layout: col=lane&15, row=g*4+j.
    #pragma unroll
    for (int m = 0; m < 4; ++m) {
        int bb = wb + m * 16 + g * 4;
        #pragma unroll
        for (int n = 0; n < 2; ++n) {
            float muv = mu[wv + n * 16 + r];
            size_t col = (size_t)(vbase + wv + n * 16 + r);
            #pragma unroll
            for (int j = 0; j < 4; ++j)
                out[(size_t)(bb + j) * V + col] = muv + __logf(acc[m][n][j]);
        }
    }
}

extern "C" void kernel_launch(void* const* d_in, const int* in_sizes, int n_in,
                              void* d_out, int out_size, void* d_ws, size_t ws_size,
                              hipStream_t stream) {
    const float* inp = (const float*)d_in[0];  // (B, T) f32
    const float* w   = (const float*)d_in[1];  // (T, V) f32
    float* out = (float*)d_out;                // (B, V) f32
    unsigned* ws = (unsigned*)d_ws;

    unsigned* Ea = ws + WS_EA;
    float* pm = (float*)(ws + WS_PM);
    float* ps = (float*)(ws + WS_PS);
    float* gt = (float*)(ws + WS_GT);

    k_stage1<<<dim3(T * KPARTS + 1), dim3(256), 0, stream>>>(inp, w, pm, ps, gt, Ea);
    k_main<<<dim3(V / VC), dim3(256), 0, stream>>>(w, pm, ps, gt, Ea, out);
}

// Round 6
// 30.076 us; speedup vs baseline: 2.4711x; 1.1517x over previous
//
#include <hip/hip_runtime.h>
#include <math.h>

// LDAWordGenerator: z[b,v] = logsumexp_t(log_theta[b,t] + log_phi[t,v])
// Factored: z = mu_v + log( sum_t Ea[b,t] * Ew[t,v] )
//   Ea[b][t] = exp(log_theta[b,t] - g_t),  g_t = max_b log_theta[b,t]
//   Ew[t][v] = exp(w[t,v] + c_t - mu_v),   c_t = g_t - lse_w[t]
//   mu_v = max_t (w[t,v] + c_t)  -> dominant term has Ew=1, Ea >= e^-spread: safe.
// Matmul over t via bf16 MFMA. B=128, T=128, V=32000.

constexpr int B = 128;
constexpr int T = 128;
constexpr int V = 32000;
constexpr int VC = 64;            // V-columns per k_main block
constexpr int KPARTS = 4;
constexpr int PART = V / KPARTS;  // 8000

// ws layout (32-bit words): EaPacked[8192] | pm[512] | ps[512] | gt[128]
constexpr int WS_EA = 0;
constexpr int WS_PM = 8192;
constexpr int WS_PS = WS_PM + T * KPARTS;
constexpr int WS_GT = WS_PS + T * KPARTS;

typedef __attribute__((ext_vector_type(8))) short bf16x8;
typedef __attribute__((ext_vector_type(4))) float f32x4;
typedef __attribute__((ext_vector_type(4))) unsigned u32x4;

__device__ inline unsigned short f2bf(float f) {
    union { float f; unsigned u; } x; x.f = f;
    unsigned u = x.u + 0x7fff + ((x.u >> 16) & 1);   // round-to-nearest-even
    return (unsigned short)(u >> 16);
}

// Swizzled word index within a 64-word (256B) row: 16B-group (tp>>2) XOR (row&15).
__device__ inline int swz_word(int row, int tp) {
    return (((tp >> 2) ^ (row & 15)) << 2) | (tp & 3);
}

// ---------------- KA: block 0 = prep; blocks 1..512 = lse_w partials (2-pass) ----
__global__ __launch_bounds__(256) void k_stage1(const float* __restrict__ inp,
                                                const float* __restrict__ w,
                                                float* __restrict__ pm,
                                                float* __restrict__ ps,
                                                float* __restrict__ gt_out,
                                                unsigned* __restrict__ Ea) {
    __shared__ float sh[B * (T + 1)];   // prep: si[b][t] at sh[b*129+t], lse_in at col 128
    __shared__ float gts[T];
    const int tid = threadIdx.x;

    if (blockIdx.x != 0) {
        const int bid = blockIdx.x - 1;
        const int t = bid >> 2;
        const int part = bid & 3;
        const float4* row = (const float4*)(w + (size_t)t * V + (size_t)part * PART);

        // pass 1: block max (pure fmax)
        float m = -INFINITY;
        for (int i = tid; i < PART / 4; i += 256) {
            float4 x4 = row[i];
            m = fmaxf(fmaxf(m, fmaxf(x4.x, x4.y)), fmaxf(x4.z, x4.w));
        }
        float* sm = sh;
        sm[tid] = m;
        __syncthreads();
        for (int off = 128; off > 0; off >>= 1) {
            if (tid < off) sm[tid] = fmaxf(sm[tid], sm[tid + off]);
            __syncthreads();
        }
        const float M = sm[0];

        // pass 2: sum of exp(x - M), rows are L2-warm
        float s = 0.f;
        for (int i = tid; i < PART / 4; i += 256) {
            float4 x4 = row[i];
            s += __expf(x4.x - M) + __expf(x4.y - M) + __expf(x4.z - M) + __expf(x4.w - M);
        }
        float* ss = sh + 256;
        ss[tid] = s;
        __syncthreads();
        for (int off = 128; off > 0; off >>= 1) {
            if (tid < off) ss[tid] += ss[tid + off];
            __syncthreads();
        }
        if (tid == 0) { pm[bid] = M; ps[bid] = ss[0]; }
        return;
    }

    // ---- prep block ----
    #pragma unroll
    for (int k = 0; k < 16; ++k) {
        int i4 = tid + k * 256;
        float4 x = ((const float4*)inp)[i4];
        int r = i4 >> 5, c = (i4 & 31) * 4;
        float* dst = &sh[r * 129 + c];
        dst[0] = x.x; dst[1] = x.y; dst[2] = x.z; dst[3] = x.w;
    }
    __syncthreads();

    if (tid < B) {   // lse_in[b] -> pad column 128
        const int b = tid;
        const float* row = &sh[b * 129];
        float m = -INFINITY;
        for (int t = 0; t < T; ++t) m = fmaxf(m, row[t]);
        float s = 0.f;
        for (int t = 0; t < T; ++t) s += __expf(row[t] - m);
        sh[b * 129 + 128] = m + logf(s);
    }
    __syncthreads();

    if (tid < T) {   // g_t = max_b(inp[b][t] - lse_in[b])
        const int t = tid;
        float g = -INFINITY;
        for (int b = 0; b < B; ++b) g = fmaxf(g, sh[b * 129 + t] - sh[b * 129 + 128]);
        gts[t] = g;
        gt_out[t] = g;
    }
    __syncthreads();

    if (tid < B) {   // pack Ea bf16 pairs in place into row b (swizzled)
        const int b = tid;
        const float li = sh[b * 129 + 128];
        unsigned pk[64];
        #pragma unroll
        for (int tp = 0; tp < 64; ++tp) {
            float e0 = __expf(sh[b * 129 + 2 * tp]     - li - gts[2 * tp]);
            float e1 = __expf(sh[b * 129 + 2 * tp + 1] - li - gts[2 * tp + 1]);
            pk[tp] = (unsigned)f2bf(e0) | ((unsigned)f2bf(e1) << 16);
        }
        unsigned* row = (unsigned*)&sh[b * 129];
        #pragma unroll
        for (int tp = 0; tp < 64; ++tp) row[swz_word(b, tp)] = pk[tp];
    }
    __syncthreads();

    #pragma unroll
    for (int k = 0; k < 32; ++k) {   // coalesced copy-out
        int d = tid + k * 256;
        int b = d >> 6, wsw = d & 63;
        Ea[d] = ((unsigned*)&sh[b * 129])[wsw];
    }
}

// ---------------- KB: register-staged w, mu reduce, Ew pack, MFMA, epilogue ----------------
__global__ __launch_bounds__(256) void k_main(const float* __restrict__ w,
                                              const float* __restrict__ pm,
                                              const float* __restrict__ ps,
                                              const float* __restrict__ gt,
                                              const unsigned* __restrict__ Ea_g,
                                              float* __restrict__ out) {
    __shared__ unsigned EaL[B * 64];    // 32 KiB, swizzled [b][tp]
    __shared__ unsigned EwL[VC * 64];   // 16 KiB, swizzled [v][tp]
    __shared__ float cs[T];
    __shared__ float mu[VC];
    __shared__ float pmT[VC][17];       // mu partials [v][tq], pad 17 -> conflict-free

    const int tid = threadIdx.x;
    const int vbase = blockIdx.x * VC;
    const int v4 = tid & 15;            // owns v = v4*4 .. v4*4+3
    const int tq = tid >> 4;            // owns t = tq*8 .. tq*8+7

    // issue the block's whole w slab into registers: 8 x float4 per thread
    f32x4 wr[8];
    {
        const float* wp = w + (size_t)(tq * 8) * V + vbase + v4 * 4;
        #pragma unroll
        for (int i = 0; i < 8; ++i)
            wr[i] = *(const f32x4*)(wp + (size_t)i * V);
    }

    if (tid < T) {   // c_t = g_t - lse_w[t]
        const int t = tid;
        float M = pm[t * KPARTS];
        #pragma unroll
        for (int p = 1; p < KPARTS; ++p) M = fmaxf(M, pm[t * KPARTS + p]);
        float S = 0.f;
        #pragma unroll
        for (int p = 0; p < KPARTS; ++p) S += ps[t * KPARTS + p] * __expf(pm[t * KPARTS + p] - M);
        cs[t] = gt[t] - (M + logf(S));
    }

    // stage Ea (pre-swizzled in ws): linear 32 KiB copy
    {
        const float4* src = (const float4*)Ea_g;
        float4* dst = (float4*)EaL;
        #pragma unroll
        for (int k = 0; k < 8; ++k) dst[tid + k * 256] = src[tid + k * 256];
    }
    __syncthreads();   // cs ready, wr loaded (waitcnt before use)

    // mu partials from registers: p[c] = max_i (wr[i][c] + cs[tq*8+i])
    {
        float p0 = -INFINITY, p1 = -INFINITY, p2 = -INFINITY, p3 = -INFINITY;
        #pragma unroll
        for (int i = 0; i < 8; ++i) {
            const float cc = cs[tq * 8 + i];
            p0 = fmaxf(p0, wr[i][0] + cc);
            p1 = fmaxf(p1, wr[i][1] + cc);
            p2 = fmaxf(p2, wr[i][2] + cc);
            p3 = fmaxf(p3, wr[i][3] + cc);
        }
        pmT[v4 * 4 + 0][tq] = p0;
        pmT[v4 * 4 + 1][tq] = p1;
        pmT[v4 * 4 + 2][tq] = p2;
        pmT[v4 * 4 + 3][tq] = p3;
    }
    __syncthreads();
    if (tid < VC) {
        float m = pmT[tid][0];
        #pragma unroll
        for (int r = 1; r < 16; ++r) m = fmaxf(m, pmT[tid][r]);
        mu[tid] = m;
    }
    __syncthreads();

    // Ew from registers: exp(w + c - mu), pack bf16 pairs, swizzled 16B writes
    {
        #pragma unroll
        for (int c = 0; c < 4; ++c) {
            const int v = v4 * 4 + c;
            const float m_ = mu[v];
            unsigned pk[4];
            #pragma unroll
            for (int p2 = 0; p2 < 4; ++p2) {
                float e0 = __expf(wr[2 * p2][c]     + cs[tq * 8 + 2 * p2]     - m_);
                float e1 = __expf(wr[2 * p2 + 1][c] + cs[tq * 8 + 2 * p2 + 1] - m_);
                pk[p2] = (unsigned)f2bf(e0) | ((unsigned)f2bf(e1) << 16);
            }
            *(u32x4*)&EwL[v * 64 + ((tq ^ (v & 15)) << 2)] = (u32x4){pk[0], pk[1], pk[2], pk[3]};
        }
    }
    __syncthreads();

    // MFMA: C[b][v] = sum_t Ea[b][t]*Ew^T[v][t]. 4 waves, each 64b x 32v.
    const int lane = tid & 63;
    const int wave = tid >> 6;
    const int wb = (wave >> 1) * 64;
    const int wv = (wave & 1) * 32;
    const int r = lane & 15;
    const int g = lane >> 4;

    f32x4 acc[4][2];
    #pragma unroll
    for (int m = 0; m < 4; ++m)
        #pragma unroll
        for (int n = 0; n < 2; ++n) acc[m][n] = (f32x4){0.f, 0.f, 0.f, 0.f};

    #pragma unroll
    for (int kk = 0; kk < 4; ++kk) {
        const int grp = kk * 4 + g;
        bf16x8 af[4], bfr[2];
        #pragma unroll
        for (int m = 0; m < 4; ++m) {
            int bb = wb + m * 16 + r;
            af[m] = *(const bf16x8*)((const char*)EaL + bb * 256 + ((grp ^ (bb & 15)) << 4));
        }
        #pragma unroll
        for (int n = 0; n < 2; ++n) {
            int vv = wv + n * 16 + r;
            bfr[n] = *(const bf16x8*)((const char*)EwL + vv * 256 + ((grp ^ (vv & 15)) << 4));
        }
        #pragma unroll
        for (int m = 0; m < 4; ++m)
            #pragma unroll
            for (int n = 0; n < 2; ++n)
                acc[m][n] = __builtin_amdgcn_mfma_f32_16x16x32_bf16(af[m], bfr[n], acc[m][n], 0, 0, 0);
    }

    // epilogue: z = mu_v + log(P). C layout: col=lane&15, row=g*4+j.
    #pragma unroll
    for (int m = 0; m < 4; ++m) {
        int bb = wb + m * 16 + g * 4;
        #pragma unroll
        for (int n = 0; n < 2; ++n) {
            float muv = mu[wv + n * 16 + r];
            size_t col = (size_t)(vbase + wv + n * 16 + r);
            #pragma unroll
            for (int j = 0; j < 4; ++j)
                out[(size_t)(bb + j) * V + col] = muv + __logf(acc[m][n][j]);
        }
    }
}

extern "C" void kernel_launch(void* const* d_in, const int* in_sizes, int n_in,
                              void* d_out, int out_size, void* d_ws, size_t ws_size,
                              hipStream_t stream) {
    const float* inp = (const float*)d_in[0];  // (B, T) f32
    const float* w   = (const float*)d_in[1];  // (T, V) f32
    float* out = (float*)d_out;                // (B, V) f32
    unsigned* ws = (unsigned*)d_ws;

    unsigned* Ea = ws + WS_EA;
    float* pm = (float*)(ws + WS_PM);
    float* ps = (float*)(ws + WS_PS);
    float* gt = (float*)(ws + WS_GT);

    k_stage1<<<dim3(T * KPARTS + 1), dim3(256), 0, stream>>>(inp, w, pm, ps, gt, Ea);
    k_main<<<dim3(V / VC), dim3(256), 0, stream>>>(w, pm, ps, gt, Ea, out);
}